// Round 19
// baseline (1302.533 us; speedup 1.0000x reference)
//
#include <hip/hip_runtime.h>
#include <stdint.h>

#define DD 128
#define LDSROW 136  // 128 cols + 8 pad (ushort) -> 272B row stride
#define NBLK 1024   // persistent grid: 4 blocks/CU x 256 CUs, co-resident by construction

typedef __attribute__((ext_vector_type(8))) short short8;
typedef __attribute__((ext_vector_type(4))) float float4v;

// ---------- bf16 helpers (RTNE) ----------
__device__ __forceinline__ unsigned short f2bf(float f) {
  unsigned u = __float_as_uint(f);
  unsigned r = u + 0x7fffu + ((u >> 16) & 1u);
  return (unsigned short)(r >> 16);
}
__device__ __forceinline__ unsigned pack2(float a, float b) {
  return (unsigned)f2bf(a) | ((unsigned)f2bf(b) << 16);
}
__device__ __forceinline__ float2 unpack2(unsigned p) {
  float2 r;
  r.x = __uint_as_float(p << 16);
  r.y = __uint_as_float(p & 0xffff0000u);
  return r;
}

// ---------- device-wide single-use barrier (flag/spin pattern validated in k_scan_all) ----------
__device__ __forceinline__ void gridbar(int* cnt, int* flg, int nb) {
  __syncthreads();
  if (threadIdx.x == 0) {
    __threadfence();                       // release
    int old = atomicAdd(cnt, 1);
    if (old == nb - 1) {
      atomicExch(flg, 1);
    } else {
      while (atomicAdd(flg, 0) == 0) { __builtin_amdgcn_s_sleep(16); }
    }
  }
  __syncthreads();
  __threadfence();                         // acquire (all threads)
}

// ---------- persistent mega-kernel: CSR build + fc_in + 3 SAGE layers, 7 internal barriers ----------
__global__ __launch_bounds__(256, 4) void k_mega(
    const int* __restrict__ src, const int* __restrict__ dst,
    const float* __restrict__ h,
    const float* __restrict__ W1, const float* __restrict__ b1,
    const float* __restrict__ W2, const float* __restrict__ b2,
    const float* __restrict__ Wself, const float* __restrict__ bself,
    const float* __restrict__ Wneigh,
    unsigned* __restrict__ wfrag,
    unsigned* __restrict__ actA, unsigned* __restrict__ actB,
    unsigned short* __restrict__ esrc, unsigned short* __restrict__ erank,
    int* deg, int* __restrict__ incl, int* __restrict__ tsum, int* __restrict__ boffG,
    int* __restrict__ rowstart,
    int* cnt, int* flg, int* wq,
    float* __restrict__ out,
    int n, int e) {
  __shared__ unsigned short sT[64 * LDSROW];  // 17408 B; aliased per phase
  __shared__ int svb;
  int tid = threadIdx.x;
  const int eb = (e + 255) >> 8;
  const int nts = (n + 255) >> 8;
  const int gb = (n + 63) >> 6;
  const int lb = (n + 15) >> 4;

  // ---- Phase A: deg atomics + erank + weight-fragment prep ----
  for (int vb = blockIdx.x; vb < eb + 256; vb += NBLK) {
    if (vb < eb) {
      int i = vb * 256 + tid;
      if (i < e) erank[i] = (unsigned short)atomicAdd(&deg[dst[i]], 1);
    } else {
      int gid = (vb - eb) * 256 + tid;  // 0..65535
      int m = gid >> 13;
      int r = gid & 8191;
      int p = r & 3;
      int lane = (r >> 2) & 63;
      int t = (r >> 8) & 3;
      int c = r >> 10;
      const float* W;
      if (m == 0) W = W1;
      else if (m == 1) W = W2;
      else if (m < 5) W = Wself + (size_t)(m - 2) * DD * DD;
      else W = Wneigh + (size_t)(m - 5) * DD * DD;
      int nc = c * 16 + (lane & 15);
      int k = t * 32 + (lane >> 4) * 8 + 2 * p;
      wfrag[gid] = pack2(W[(size_t)k * DD + nc], W[(size_t)(k + 1) * DD + nc]);
    }
  }
  gridbar(cnt + 0, flg + 0, NBLK);

  // ---- B1: per-256-tile inclusive scan of deg ----
  int* shi = (int*)sT;
  for (int vb = blockIdx.x; vb < nts; vb += NBLK) {
    int i = vb * 256 + tid;
    int v = (i < n) ? deg[i] : 0;
    shi[tid] = v;
    __syncthreads();
#pragma unroll
    for (int off = 1; off < 256; off <<= 1) {
      int add = (tid >= off) ? shi[tid - off] : 0;
      __syncthreads();
      shi[tid] += add;
      __syncthreads();
    }
    if (i < n) incl[i] = shi[tid];
    if (tid == 255) tsum[vb] = shi[255];
    __syncthreads();
  }
  gridbar(cnt + 1, flg + 1, NBLK);

  // ---- B2: block 0 scans the nts tile sums ----
  if (blockIdx.x == 0) {
    int v = (tid < nts) ? tsum[tid] : 0;
    shi[tid] = v;
    __syncthreads();
#pragma unroll
    for (int off = 1; off < 256; off <<= 1) {
      int add = (tid >= off) ? shi[tid - off] : 0;
      __syncthreads();
      shi[tid] += add;
      __syncthreads();
    }
    if (tid < nts) boffG[tid] = shi[tid] - v;  // exclusive
    if (tid == nts - 1) rowstart[n] = shi[tid];
    __syncthreads();
  }
  gridbar(cnt + 2, flg + 2, NBLK);

  // ---- B3: write rowstart ----
  for (int vb = blockIdx.x; vb < nts; vb += NBLK) {
    int i = vb * 256 + tid;
    if (i < n) rowstart[i] = boffG[vb] + incl[i] - deg[i];
  }
  gridbar(cnt + 3, flg + 3, NBLK);

  // ---- Phase C: fc12 tiles [0,gb) + fill tiles [gb,gb+eb) via work queue ----
  const uint4* wf1 = (const uint4*)wfrag;
  const uint4* wf2 = wf1 + 2048;
  while (true) {
    if (tid == 0) svb = atomicAdd(&wq[0], 1);
    __syncthreads();
    int vb = svb;
    __syncthreads();
    if (vb >= gb + eb) break;
    if (vb >= gb) {  // fill tile
      int i = (vb - gb) * 256 + tid;
      if (i < e) {
        int d = dst[i];
        esrc[rowstart[d] + (int)erank[i]] = (unsigned short)src[i];
      }
      __syncthreads();
      continue;
    }
    // fc12 tile vb: 64 rows
    {
      int w = tid >> 6, lane = tid & 63;
      int q = lane >> 4, nn = lane & 15;
      int r0 = (vb * 4 + w) * 16;
      int rr = r0 + nn; if (rr >= n) rr = n - 1;
      short8 a[4];
      {
        const float* X = h + (size_t)rr * DD;
#pragma unroll
        for (int t = 0; t < 4; ++t) {
          int k0 = t * 32 + q * 8;
          float4 f0 = *(const float4*)&X[k0];
          float4 f1 = *(const float4*)&X[k0 + 4];
          uint4 u;
          u.x = pack2(f0.x, f0.y); u.y = pack2(f0.z, f0.w);
          u.z = pack2(f1.x, f1.y); u.w = pack2(f1.z, f1.w);
          a[t] = __builtin_bit_cast(short8, u);
        }
      }
      float4v acc[8];
#pragma unroll
      for (int c = 0; c < 8; ++c) acc[c] = (float4v){0.f, 0.f, 0.f, 0.f};
#pragma unroll
      for (int c = 0; c < 8; ++c) {
#pragma unroll
        for (int t = 0; t < 4; ++t) {
          short8 bb = __builtin_bit_cast(short8, wf1[(c * 4 + t) * 64 + lane]);
          acc[c] = __builtin_amdgcn_mfma_f32_16x16x32_bf16(a[t], bb, acc[c], 0, 0, 0);
        }
      }
#pragma unroll
      for (int c = 0; c < 8; ++c) {
        float bc = b1[c * 16 + nn];
#pragma unroll
        for (int g = 0; g < 4; ++g) {
          int lr = w * 16 + q * 4 + g;
          sT[lr * LDSROW + c * 16 + nn] = f2bf(tanhf(acc[c][g] + bc));
        }
      }
      __syncthreads();
      short8 a2[4];
#pragma unroll
      for (int t = 0; t < 4; ++t) {
        const uint4* p = (const uint4*)&sT[(w * 16 + nn) * LDSROW + (t * 4 + q) * 8];
        a2[t] = __builtin_bit_cast(short8, *p);
      }
      float4v acc2[8];
#pragma unroll
      for (int c = 0; c < 8; ++c) acc2[c] = (float4v){0.f, 0.f, 0.f, 0.f};
#pragma unroll
      for (int c = 0; c < 8; ++c) {
#pragma unroll
        for (int t = 0; t < 4; ++t) {
          short8 bb = __builtin_bit_cast(short8, wf2[(c * 4 + t) * 64 + lane]);
          acc2[c] = __builtin_amdgcn_mfma_f32_16x16x32_bf16(a2[t], bb, acc2[c], 0, 0, 0);
        }
      }
      unsigned short* outbf = (unsigned short*)actB;
#pragma unroll
      for (int c = 0; c < 8; ++c) {
        float bc = b2[c * 16 + nn];
#pragma unroll
        for (int g = 0; g < 4; ++g) {
          int row = r0 + q * 4 + g;
          if (row < n) outbf[(size_t)row * DD + c * 16 + nn] = f2bf(acc2[c][g] + bc);
        }
      }
      __syncthreads();
    }
  }
  gridbar(cnt + 4, flg + 4, NBLK);

  // ---- Layers 0..2 via work queues ----
  for (int l = 0; l < 3; ++l) {
    const uint4* X = (const uint4*)((l == 1) ? actA : actB);
    unsigned short* O16 = (l == 0) ? (unsigned short*)actA : (unsigned short*)actB;
    const uint4* wfs = wf1 + (size_t)(2 + l) * 2048;
    const uint4* wfn = wf1 + (size_t)(5 + l) * 2048;
    const float* bs = bself + (size_t)l * DD;
    unsigned short* sG = sT;  // 16*136 ushorts
    while (true) {
      if (tid == 0) svb = atomicAdd(&wq[1 + l], 1);
      __syncthreads();
      int vb = svb;
      __syncthreads();
      if (vb >= lb) break;
      int grp = tid >> 4, nng = tid & 15;
      int r0 = vb * 16;
      int r = r0 + grp;
      if (r < n) {
        int beg = rowstart[r];
        int cntr = rowstart[r + 1] - beg;
        float acc[8];
#pragma unroll
        for (int i = 0; i < 8; ++i) acc[i] = 0.f;
        int base = 0;
        for (; base + 8 <= cntr; base += 8) {
          int j0 = beg + base;
          int s0 = esrc[j0], s1 = esrc[j0 + 1], s2 = esrc[j0 + 2], s3 = esrc[j0 + 3];
          int s4 = esrc[j0 + 4], s5 = esrc[j0 + 5], s6 = esrc[j0 + 6], s7 = esrc[j0 + 7];
          uint4 v0 = X[(size_t)s0 * 16 + nng];
          uint4 v1 = X[(size_t)s1 * 16 + nng];
          uint4 v2 = X[(size_t)s2 * 16 + nng];
          uint4 v3 = X[(size_t)s3 * 16 + nng];
          uint4 v4 = X[(size_t)s4 * 16 + nng];
          uint4 v5 = X[(size_t)s5 * 16 + nng];
          uint4 v6 = X[(size_t)s6 * 16 + nng];
          uint4 v7 = X[(size_t)s7 * 16 + nng];
          const unsigned* u0 = (const unsigned*)&v0;
          const unsigned* u1 = (const unsigned*)&v1;
          const unsigned* u2 = (const unsigned*)&v2;
          const unsigned* u3 = (const unsigned*)&v3;
          const unsigned* u4 = (const unsigned*)&v4;
          const unsigned* u5 = (const unsigned*)&v5;
          const unsigned* u6 = (const unsigned*)&v6;
          const unsigned* u7 = (const unsigned*)&v7;
#pragma unroll
          for (int k = 0; k < 4; ++k) {
            float2 f0 = unpack2(u0[k]), f1 = unpack2(u1[k]);
            float2 f2 = unpack2(u2[k]), f3 = unpack2(u3[k]);
            float2 f4 = unpack2(u4[k]), f5 = unpack2(u5[k]);
            float2 f6 = unpack2(u6[k]), f7 = unpack2(u7[k]);
            acc[2 * k]     += ((f0.x + f1.x) + (f2.x + f3.x)) + ((f4.x + f5.x) + (f6.x + f7.x));
            acc[2 * k + 1] += ((f0.y + f1.y) + (f2.y + f3.y)) + ((f4.y + f5.y) + (f6.y + f7.y));
          }
        }
        if (base < cntr) {  // masked 8-wide tail
          int last = beg + cntr - 1;
          int j0 = beg + base;
          int i1 = j0 + 1 <= last ? j0 + 1 : last;
          int i2 = j0 + 2 <= last ? j0 + 2 : last;
          int i3 = j0 + 3 <= last ? j0 + 3 : last;
          int i4 = j0 + 4 <= last ? j0 + 4 : last;
          int i5 = j0 + 5 <= last ? j0 + 5 : last;
          int i6 = j0 + 6 <= last ? j0 + 6 : last;
          int i7 = j0 + 7 <= last ? j0 + 7 : last;
          float w1 = (base + 1 < cntr) ? 1.f : 0.f;
          float w2 = (base + 2 < cntr) ? 1.f : 0.f;
          float w3 = (base + 3 < cntr) ? 1.f : 0.f;
          float w4 = (base + 4 < cntr) ? 1.f : 0.f;
          float w5 = (base + 5 < cntr) ? 1.f : 0.f;
          float w6 = (base + 6 < cntr) ? 1.f : 0.f;
          float w7 = (base + 7 < cntr) ? 1.f : 0.f;
          int s0 = esrc[j0], s1 = esrc[i1], s2 = esrc[i2], s3 = esrc[i3];
          int s4 = esrc[i4], s5 = esrc[i5], s6 = esrc[i6], s7 = esrc[i7];
          uint4 v0 = X[(size_t)s0 * 16 + nng];
          uint4 v1 = X[(size_t)s1 * 16 + nng];
          uint4 v2 = X[(size_t)s2 * 16 + nng];
          uint4 v3 = X[(size_t)s3 * 16 + nng];
          uint4 v4 = X[(size_t)s4 * 16 + nng];
          uint4 v5 = X[(size_t)s5 * 16 + nng];
          uint4 v6 = X[(size_t)s6 * 16 + nng];
          uint4 v7 = X[(size_t)s7 * 16 + nng];
          const unsigned* u0 = (const unsigned*)&v0;
          const unsigned* u1 = (const unsigned*)&v1;
          const unsigned* u2 = (const unsigned*)&v2;
          const unsigned* u3 = (const unsigned*)&v3;
          const unsigned* u4 = (const unsigned*)&v4;
          const unsigned* u5 = (const unsigned*)&v5;
          const unsigned* u6 = (const unsigned*)&v6;
          const unsigned* u7 = (const unsigned*)&v7;
#pragma unroll
          for (int k = 0; k < 4; ++k) {
            float2 f0 = unpack2(u0[k]), f1 = unpack2(u1[k]);
            float2 f2 = unpack2(u2[k]), f3 = unpack2(u3[k]);
            float2 f4 = unpack2(u4[k]), f5 = unpack2(u5[k]);
            float2 f6 = unpack2(u6[k]), f7 = unpack2(u7[k]);
            acc[2 * k]     += ((f0.x + w1 * f1.x) + (w2 * f2.x + w3 * f3.x)) + ((w4 * f4.x + w5 * f5.x) + (w6 * f6.x + w7 * f7.x));
            acc[2 * k + 1] += ((f0.y + w1 * f1.y) + (w2 * f2.y + w3 * f3.y)) + ((w4 * f4.y + w5 * f5.y) + (w6 * f6.y + w7 * f7.y));
          }
        }
        float inv = 1.0f / (float)(cntr > 1 ? cntr : 1);
        uint4 o;
        o.x = pack2(acc[0] * inv, acc[1] * inv);
        o.y = pack2(acc[2] * inv, acc[3] * inv);
        o.z = pack2(acc[4] * inv, acc[5] * inv);
        o.w = pack2(acc[6] * inv, acc[7] * inv);
        *(uint4*)&sG[grp * LDSROW + nng * 8] = o;
      }
      __syncthreads();
      // phase 2: SAGE GEMM, wave w -> col-chunks {2w,2w+1}
      {
        int w = tid >> 6, lane = tid & 63;
        int q = lane >> 4, nn16 = lane & 15;
        int rr = r0 + nn16; if (rr >= n) rr = n - 1;
        short8 a[4], gf[4];
        const uint4* Xr = X + (size_t)rr * 16;
#pragma unroll
        for (int t = 0; t < 4; ++t) {
          a[t] = __builtin_bit_cast(short8, Xr[t * 4 + q]);
          gf[t] = __builtin_bit_cast(short8, *(const uint4*)&sG[nn16 * LDSROW + (t * 4 + q) * 8]);
        }
        float4v acc2[2];
#pragma unroll
        for (int cc = 0; cc < 2; ++cc) acc2[cc] = (float4v){0.f, 0.f, 0.f, 0.f};
#pragma unroll
        for (int cc = 0; cc < 2; ++cc) {
          int c = 2 * w + cc;
#pragma unroll
          for (int t = 0; t < 4; ++t) {
            short8 b = __builtin_bit_cast(short8, wfs[(c * 4 + t) * 64 + lane]);
            acc2[cc] = __builtin_amdgcn_mfma_f32_16x16x32_bf16(a[t], b, acc2[cc], 0, 0, 0);
          }
#pragma unroll
          for (int t = 0; t < 4; ++t) {
            short8 b = __builtin_bit_cast(short8, wfn[(c * 4 + t) * 64 + lane]);
            acc2[cc] = __builtin_amdgcn_mfma_f32_16x16x32_bf16(gf[t], b, acc2[cc], 0, 0, 0);
          }
        }
#pragma unroll
        for (int cc = 0; cc < 2; ++cc) {
          int c = 2 * w + cc;
          float bc = bs[c * 16 + nn16];
#pragma unroll
          for (int gg = 0; gg < 4; ++gg) {
            int row = r0 + q * 4 + gg;
            if (row < n) {
              float v = acc2[cc][gg] + bc;
              if (l == 2) {
                v = tanhf(v);
                out[(size_t)row * DD + c * 16 + nn16] = v;
              } else {
                v = v / (1.f + __expf(-v));
                O16[(size_t)row * DD + c * 16 + nn16] = f2bf(v);
              }
            }
          }
        }
      }
      __syncthreads();
    }
    if (l < 2) gridbar(cnt + 5 + l, flg + 5 + l, NBLK);
  }
}

extern "C" void kernel_launch(void* const* d_in, const int* in_sizes, int n_in,
                              void* d_out, int out_size, void* d_ws, size_t ws_size,
                              hipStream_t stream) {
  const float* h_in = (const float*)d_in[0];
  const int* src    = (const int*)d_in[1];
  const int* dst    = (const int*)d_in[2];
  const float* W1   = (const float*)d_in[3];
  const float* b1   = (const float*)d_in[4];
  const float* W2   = (const float*)d_in[5];
  const float* b2   = (const float*)d_in[6];
  const float* Wself  = (const float*)d_in[7];
  const float* bself  = (const float*)d_in[8];
  const float* Wneigh = (const float*)d_in[9];
  const int N = in_sizes[0] / DD;
  const int E = in_sizes[1];
  float* out = (float*)d_out;

  char* ws = (char*)d_ws;
  size_t off = 0;
  auto alloc = [&](size_t bytes) -> char* {
    char* p = ws + off;
    off = (off + bytes + 255) & ~(size_t)255;
    return p;
  };
  unsigned* wfrag = (unsigned*)alloc(8 * 32768);
  unsigned* actA  = (unsigned*)alloc((size_t)N * 64 * 4);
  unsigned* actB  = (unsigned*)alloc((size_t)N * 64 * 4);
  unsigned short* esrc  = (unsigned short*)alloc((size_t)E * 2);
  unsigned short* erank = (unsigned short*)alloc((size_t)E * 2);
  int* degz     = (int*)alloc(((size_t)N + 32) * 4);  // deg + cnt[8] + flg[8] + wq[8], zeroed together
  int* degi     = degz;
  int* cnt      = degz + N;
  int* flg      = degz + N + 8;
  int* wq       = degz + N + 16;
  int* rowstart = (int*)alloc((size_t)(N + 1) * 4);
  int* incl     = (int*)alloc((size_t)N * 4);
  int* tsum     = (int*)alloc(256 * 4);
  int* boffG    = (int*)alloc(256 * 4);

  hipMemsetAsync(degz, 0, ((size_t)N + 32) * 4, stream);
  k_mega<<<NBLK, 256, 0, stream>>>(src, dst, h_in, W1, b1, W2, b2, Wself, bself, Wneigh,
                                   wfrag, actA, actB, esrc, erank,
                                   degi, incl, tsum, boffG, rowstart,
                                   cnt, flg, wq, out, N, E);
}

// Round 20
// 308.544 us; speedup vs baseline: 4.2215x; 4.2215x over previous
//
#include <hip/hip_runtime.h>
#include <stdint.h>

#define DD 128
#define LDSROW 136  // 128 cols + 8 pad (ushort) -> 272B row stride

typedef __attribute__((ext_vector_type(8))) short short8;
typedef __attribute__((ext_vector_type(4))) float float4v;

// ---------- bf16 helpers (RTNE) ----------
__device__ __forceinline__ unsigned short f2bf(float f) {
  unsigned u = __float_as_uint(f);
  unsigned r = u + 0x7fffu + ((u >> 16) & 1u);
  return (unsigned short)(r >> 16);
}
__device__ __forceinline__ unsigned pack2(float a, float b) {
  return (unsigned)f2bf(a) | ((unsigned)f2bf(b) << 16);
}
__device__ __forceinline__ float2 unpack2(unsigned p) {
  float2 r;
  r.x = __uint_as_float(p << 16);
  r.y = __uint_as_float(p & 0xffff0000u);
  return r;
}

// ---------- CSR build pass A: deg atomics + per-edge rank (ushort) + weight prep fused ----------
__global__ __launch_bounds__(256) void k_deg_prep(const int* __restrict__ dst, int* deg,
                                                  unsigned short* __restrict__ erank,
                                                  int e, int eb,
                                                  const float* __restrict__ W1, const float* __restrict__ W2,
                                                  const float* __restrict__ Wself, const float* __restrict__ Wneigh,
                                                  unsigned* __restrict__ wfrag) {
  int b = blockIdx.x;
  if (b < eb) {
    int i = b * 256 + threadIdx.x;
    if (i < e) erank[i] = (unsigned short)atomicAdd(&deg[dst[i]], 1);
  } else {
    int gid = (b - eb) * 256 + threadIdx.x;  // 0 .. 65535
    int m = gid >> 13;
    int r = gid & 8191;
    int p = r & 3;
    int lane = (r >> 2) & 63;
    int t = (r >> 8) & 3;
    int c = r >> 10;
    const float* W;
    if (m == 0) W = W1;
    else if (m == 1) W = W2;
    else if (m < 5) W = Wself + (size_t)(m - 2) * DD * DD;
    else W = Wneigh + (size_t)(m - 5) * DD * DD;
    int n = c * 16 + (lane & 15);
    int k = t * 32 + (lane >> 4) * 8 + 2 * p;
    wfrag[gid] = pack2(W[(size_t)k * DD + n], W[(size_t)(k + 1) * DD + n]);
  }
}

// ---------- fused scan: per-block scan in registers; last-arriving block publishes offsets; all blocks write rowstart ----------
__global__ __launch_bounds__(1024) void k_scan_all(const int* __restrict__ deg, int* __restrict__ bsum,
                                                   int* __restrict__ boffG, int* __restrict__ rowstart,
                                                   int* donecnt, int* flag, int n, int nb) {
  __shared__ int sh[1024];
  __shared__ int isLast;
  __shared__ int myoff;
  int t = threadIdx.x;
  int i = blockIdx.x * 1024 + t;
  int v = (i < n) ? deg[i] : 0;
  sh[t] = v;
  __syncthreads();
#pragma unroll
  for (int off = 1; off < 1024; off <<= 1) {
    int add = (t >= off) ? sh[t - off] : 0;
    __syncthreads();
    sh[t] += add;
    __syncthreads();
  }
  if (t == 1023) bsum[blockIdx.x] = sh[1023];
  __threadfence();          // publish bsum (device scope)
  __syncthreads();
  if (t == 0) {
    int old = atomicAdd(donecnt, 1);
    isLast = (old == nb - 1);
  }
  __syncthreads();
  if (isLast) {
    // last-arriving block: all other blocks have published bsum
    __threadfence();        // acquire
    if (t < 64) {
      int orig = (t < nb) ? bsum[t] : 0;
      int v2 = orig;
#pragma unroll
      for (int off = 1; off < 64; off <<= 1) {
        int u = __shfl_up(v2, off);
        if (t >= off) v2 += u;
      }
      if (t < nb) boffG[t] = v2 - orig;   // exclusive prefix
      if (t == nb - 1) rowstart[n] = v2;  // total
    }
    __threadfence();        // publish boffG before flag
    __syncthreads();
    if (t == 0) atomicExch(flag, 1);
  } else {
    if (t == 0) {
      while (atomicAdd(flag, 0) == 0) { __builtin_amdgcn_s_sleep(8); }
    }
    __syncthreads();
    __threadfence();        // acquire boffG
  }
  if (t == 0) myoff = boffG[blockIdx.x];
  __syncthreads();
  if (i < n) rowstart[i] = myoff + sh[t] - v;  // exclusive from registers
}

// ---------- merged: fused fc_in GEMM (blocks [0,gb)) + atomic-free CSR fill (blocks [gb,gb+fb)) ----------
__global__ __launch_bounds__(256) void k_fill_fc(const int* __restrict__ src, const int* __restrict__ dst,
                                                 const unsigned short* __restrict__ erank,
                                                 const int* __restrict__ rowstart,
                                                 unsigned short* __restrict__ esrc, int e, int gb,
                                                 const float* __restrict__ h,
                                                 const uint4* __restrict__ wf1, const uint4* __restrict__ wf2,
                                                 const float* __restrict__ b1, const float* __restrict__ b2,
                                                 unsigned short* __restrict__ outbf, int n) {
  __shared__ unsigned short sT[64 * LDSROW];
  int b = blockIdx.x;
  if (b >= gb) {
    int i = (b - gb) * 256 + threadIdx.x;
    if (i < e) {
      int d = dst[i];
      int p = rowstart[d] + (int)erank[i];
      esrc[p] = (unsigned short)src[i];
    }
    return;
  }
  // ---- fc12 body ----
  int tid = threadIdx.x, w = tid >> 6, lane = tid & 63;
  int q = lane >> 4, nn = lane & 15;
  int r0 = (b * 4 + w) * 16;
  int rr = r0 + nn; if (rr >= n) rr = n - 1;
  short8 a[4];
  {
    const float* X = h + (size_t)rr * DD;
#pragma unroll
    for (int t = 0; t < 4; ++t) {
      int k0 = t * 32 + q * 8;
      float4 f0 = *(const float4*)&X[k0];
      float4 f1 = *(const float4*)&X[k0 + 4];
      uint4 u;
      u.x = pack2(f0.x, f0.y); u.y = pack2(f0.z, f0.w);
      u.z = pack2(f1.x, f1.y); u.w = pack2(f1.z, f1.w);
      a[t] = __builtin_bit_cast(short8, u);
    }
  }
  float4v acc[8];
#pragma unroll
  for (int c = 0; c < 8; ++c) acc[c] = (float4v){0.f, 0.f, 0.f, 0.f};
#pragma unroll
  for (int c = 0; c < 8; ++c) {
#pragma unroll
    for (int t = 0; t < 4; ++t) {
      short8 bb = __builtin_bit_cast(short8, wf1[(c * 4 + t) * 64 + lane]);
      acc[c] = __builtin_amdgcn_mfma_f32_16x16x32_bf16(a[t], bb, acc[c], 0, 0, 0);
    }
  }
#pragma unroll
  for (int c = 0; c < 8; ++c) {
    float bc = b1[c * 16 + nn];
#pragma unroll
    for (int g = 0; g < 4; ++g) {
      int lr = w * 16 + q * 4 + g;
      sT[lr * LDSROW + c * 16 + nn] = f2bf(tanhf(acc[c][g] + bc));
    }
  }
  __syncthreads();
  short8 a2[4];
#pragma unroll
  for (int t = 0; t < 4; ++t) {
    const uint4* p = (const uint4*)&sT[(w * 16 + nn) * LDSROW + (t * 4 + q) * 8];
    a2[t] = __builtin_bit_cast(short8, *p);
  }
  float4v acc2[8];
#pragma unroll
  for (int c = 0; c < 8; ++c) acc2[c] = (float4v){0.f, 0.f, 0.f, 0.f};
#pragma unroll
  for (int c = 0; c < 8; ++c) {
#pragma unroll
    for (int t = 0; t < 4; ++t) {
      short8 bb = __builtin_bit_cast(short8, wf2[(c * 4 + t) * 64 + lane]);
      acc2[c] = __builtin_amdgcn_mfma_f32_16x16x32_bf16(a2[t], bb, acc2[c], 0, 0, 0);
    }
  }
#pragma unroll
  for (int c = 0; c < 8; ++c) {
    float bc = b2[c * 16 + nn];
#pragma unroll
    for (int g = 0; g < 4; ++g) {
      int row = r0 + q * 4 + g;
      if (row < n) outbf[(size_t)row * DD + c * 16 + nn] = f2bf(acc2[c][g] + bc);
    }
  }
}

// ---------- fused layer, 16 rows/block: aggregate (1 row per 16-lane group, 8-deep, masked tail) -> LDS -> SAGE GEMM ----------
// ACT: 1 tanh, 2 silu
template <int ACT, bool OUTF32>
__global__ __launch_bounds__(256) void k_layer16(const uint4* __restrict__ X,
                                                 const int* __restrict__ rowstart,
                                                 const unsigned short* __restrict__ esrc,
                                                 const uint4* __restrict__ wfs, const uint4* __restrict__ wfn,
                                                 const float* __restrict__ bias, void* __restrict__ outp, int n) {
  __shared__ unsigned short sG[16 * LDSROW];
  int tid = threadIdx.x;
  int grp = tid >> 4, nn = tid & 15;   // 16 groups x 16 lanes
  int r0 = blockIdx.x * 16;
  int r = r0 + grp;
  // ---- phase 1: aggregate row r; lane nn covers bf16 cols nn*8..nn*8+7 (one uint4) ----
  if (r < n) {
    int beg = rowstart[r];
    int cnt = rowstart[r + 1] - beg;
    float acc[8];
#pragma unroll
    for (int i = 0; i < 8; ++i) acc[i] = 0.f;
    int base = 0;
    for (; base + 8 <= cnt; base += 8) {  // 8 gathers in flight
      int j0 = beg + base;
      int s0 = esrc[j0], s1 = esrc[j0 + 1], s2 = esrc[j0 + 2], s3 = esrc[j0 + 3];
      int s4 = esrc[j0 + 4], s5 = esrc[j0 + 5], s6 = esrc[j0 + 6], s7 = esrc[j0 + 7];
      uint4 v0 = X[(size_t)s0 * 16 + nn];
      uint4 v1 = X[(size_t)s1 * 16 + nn];
      uint4 v2 = X[(size_t)s2 * 16 + nn];
      uint4 v3 = X[(size_t)s3 * 16 + nn];
      uint4 v4 = X[(size_t)s4 * 16 + nn];
      uint4 v5 = X[(size_t)s5 * 16 + nn];
      uint4 v6 = X[(size_t)s6 * 16 + nn];
      uint4 v7 = X[(size_t)s7 * 16 + nn];
      const unsigned* u0 = (const unsigned*)&v0;
      const unsigned* u1 = (const unsigned*)&v1;
      const unsigned* u2 = (const unsigned*)&v2;
      const unsigned* u3 = (const unsigned*)&v3;
      const unsigned* u4 = (const unsigned*)&v4;
      const unsigned* u5 = (const unsigned*)&v5;
      const unsigned* u6 = (const unsigned*)&v6;
      const unsigned* u7 = (const unsigned*)&v7;
#pragma unroll
      for (int k = 0; k < 4; ++k) {
        float2 f0 = unpack2(u0[k]), f1 = unpack2(u1[k]);
        float2 f2 = unpack2(u2[k]), f3 = unpack2(u3[k]);
        float2 f4 = unpack2(u4[k]), f5 = unpack2(u5[k]);
        float2 f6 = unpack2(u6[k]), f7 = unpack2(u7[k]);
        acc[2 * k]     += ((f0.x + f1.x) + (f2.x + f3.x)) + ((f4.x + f5.x) + (f6.x + f7.x));
        acc[2 * k + 1] += ((f0.y + f1.y) + (f2.y + f3.y)) + ((f4.y + f5.y) + (f6.y + f7.y));
      }
    }
    if (base < cnt) {  // masked 8-wide tail: clamp index (dup gathers hit cache), weight 0/1
      int last = beg + cnt - 1;
      int j0 = beg + base;
      int i1 = j0 + 1 <= last ? j0 + 1 : last;
      int i2 = j0 + 2 <= last ? j0 + 2 : last;
      int i3 = j0 + 3 <= last ? j0 + 3 : last;
      int i4 = j0 + 4 <= last ? j0 + 4 : last;
      int i5 = j0 + 5 <= last ? j0 + 5 : last;
      int i6 = j0 + 6 <= last ? j0 + 6 : last;
      int i7 = j0 + 7 <= last ? j0 + 7 : last;
      float w1 = (base + 1 < cnt) ? 1.f : 0.f;
      float w2 = (base + 2 < cnt) ? 1.f : 0.f;
      float w3 = (base + 3 < cnt) ? 1.f : 0.f;
      float w4 = (base + 4 < cnt) ? 1.f : 0.f;
      float w5 = (base + 5 < cnt) ? 1.f : 0.f;
      float w6 = (base + 6 < cnt) ? 1.f : 0.f;
      float w7 = (base + 7 < cnt) ? 1.f : 0.f;
      int s0 = esrc[j0], s1 = esrc[i1], s2 = esrc[i2], s3 = esrc[i3];
      int s4 = esrc[i4], s5 = esrc[i5], s6 = esrc[i6], s7 = esrc[i7];
      uint4 v0 = X[(size_t)s0 * 16 + nn];
      uint4 v1 = X[(size_t)s1 * 16 + nn];
      uint4 v2 = X[(size_t)s2 * 16 + nn];
      uint4 v3 = X[(size_t)s3 * 16 + nn];
      uint4 v4 = X[(size_t)s4 * 16 + nn];
      uint4 v5 = X[(size_t)s5 * 16 + nn];
      uint4 v6 = X[(size_t)s6 * 16 + nn];
      uint4 v7 = X[(size_t)s7 * 16 + nn];
      const unsigned* u0 = (const unsigned*)&v0;
      const unsigned* u1 = (const unsigned*)&v1;
      const unsigned* u2 = (const unsigned*)&v2;
      const unsigned* u3 = (const unsigned*)&v3;
      const unsigned* u4 = (const unsigned*)&v4;
      const unsigned* u5 = (const unsigned*)&v5;
      const unsigned* u6 = (const unsigned*)&v6;
      const unsigned* u7 = (const unsigned*)&v7;
#pragma unroll
      for (int k = 0; k < 4; ++k) {
        float2 f0 = unpack2(u0[k]), f1 = unpack2(u1[k]);
        float2 f2 = unpack2(u2[k]), f3 = unpack2(u3[k]);
        float2 f4 = unpack2(u4[k]), f5 = unpack2(u5[k]);
        float2 f6 = unpack2(u6[k]), f7 = unpack2(u7[k]);
        acc[2 * k]     += ((f0.x + w1 * f1.x) + (w2 * f2.x + w3 * f3.x)) + ((w4 * f4.x + w5 * f5.x) + (w6 * f6.x + w7 * f7.x));
        acc[2 * k + 1] += ((f0.y + w1 * f1.y) + (w2 * f2.y + w3 * f3.y)) + ((w4 * f4.y + w5 * f5.y) + (w6 * f6.y + w7 * f7.y));
      }
    }
    float inv = 1.0f / (float)(cnt > 1 ? cnt : 1);
    uint4 o;
    o.x = pack2(acc[0] * inv, acc[1] * inv);
    o.y = pack2(acc[2] * inv, acc[3] * inv);
    o.z = pack2(acc[4] * inv, acc[5] * inv);
    o.w = pack2(acc[6] * inv, acc[7] * inv);
    *(uint4*)&sG[grp * LDSROW + nn * 8] = o;
  }
  __syncthreads();
  // ---- phase 2: SAGE GEMM on rows r0..r0+15. wave w -> col-chunks {2w, 2w+1} ----
  int w = tid >> 6, lane = tid & 63;
  int q = lane >> 4, nn16 = lane & 15;
  int rr = r0 + nn16; if (rr >= n) rr = n - 1;
  short8 a[4], gf[4];
  {
    const uint4* Xr = X + (size_t)rr * 16;
#pragma unroll
    for (int t = 0; t < 4; ++t) {
      a[t] = __builtin_bit_cast(short8, Xr[t * 4 + q]);
      gf[t] = __builtin_bit_cast(short8, *(const uint4*)&sG[nn16 * LDSROW + (t * 4 + q) * 8]);
    }
  }
  float4v acc2[2];
#pragma unroll
  for (int cc = 0; cc < 2; ++cc) acc2[cc] = (float4v){0.f, 0.f, 0.f, 0.f};
#pragma unroll
  for (int cc = 0; cc < 2; ++cc) {
    int c = 2 * w + cc;
#pragma unroll
    for (int t = 0; t < 4; ++t) {
      short8 b = __builtin_bit_cast(short8, wfs[(c * 4 + t) * 64 + lane]);
      acc2[cc] = __builtin_amdgcn_mfma_f32_16x16x32_bf16(a[t], b, acc2[cc], 0, 0, 0);
    }
#pragma unroll
    for (int t = 0; t < 4; ++t) {
      short8 b = __builtin_bit_cast(short8, wfn[(c * 4 + t) * 64 + lane]);
      acc2[cc] = __builtin_amdgcn_mfma_f32_16x16x32_bf16(gf[t], b, acc2[cc], 0, 0, 0);
    }
  }
#pragma unroll
  for (int cc = 0; cc < 2; ++cc) {
    int c = 2 * w + cc;
    float bc = bias[c * 16 + nn16];
#pragma unroll
    for (int gg = 0; gg < 4; ++gg) {
      int row = r0 + q * 4 + gg;
      if (row < n) {
        float v = acc2[cc][gg] + bc;
        if (ACT == 1) v = tanhf(v);
        else v = v / (1.f + __expf(-v));
        if (OUTF32) ((float*)outp)[(size_t)row * DD + c * 16 + nn16] = v;
        else ((unsigned short*)outp)[(size_t)row * DD + c * 16 + nn16] = f2bf(v);
      }
    }
  }
}

extern "C" void kernel_launch(void* const* d_in, const int* in_sizes, int n_in,
                              void* d_out, int out_size, void* d_ws, size_t ws_size,
                              hipStream_t stream) {
  const float* h_in = (const float*)d_in[0];
  const int* src    = (const int*)d_in[1];
  const int* dst    = (const int*)d_in[2];
  const float* W1   = (const float*)d_in[3];
  const float* b1   = (const float*)d_in[4];
  const float* W2   = (const float*)d_in[5];
  const float* b2   = (const float*)d_in[6];
  const float* Wself  = (const float*)d_in[7];
  const float* bself  = (const float*)d_in[8];
  const float* Wneigh = (const float*)d_in[9];
  const int N = in_sizes[0] / DD;
  const int E = in_sizes[1];
  float* out = (float*)d_out;

  char* ws = (char*)d_ws;
  size_t off = 0;
  auto alloc = [&](size_t bytes) -> char* {
    char* p = ws + off;
    off = (off + bytes + 255) & ~(size_t)255;
    return p;
  };
  unsigned* wfrag = (unsigned*)alloc(8 * 32768);
  unsigned* actA  = (unsigned*)alloc((size_t)N * 64 * 4);
  unsigned* actB  = (unsigned*)alloc((size_t)N * 64 * 4);
  unsigned short* esrc  = (unsigned short*)alloc((size_t)E * 2);
  unsigned short* erank = (unsigned short*)alloc((size_t)E * 2);
  int* degdc    = (int*)alloc(((size_t)N + 64) * 4);  // degi + donecnt + flag, zeroed together
  int* degi     = degdc;
  int* donecnt  = degdc + N;
  int* flag     = degdc + N + 1;
  int* rowstart = (int*)alloc((size_t)(N + 1) * 4);
  int* bsum     = (int*)alloc(65 * 4);
  int* boffG    = (int*)alloc(64 * 4);

  hipMemsetAsync(degdc, 0, ((size_t)N + 64) * 4, stream);
  const int eb = (E + 255) / 256;
  const int nb = (N + 1023) / 1024;
  k_deg_prep<<<eb + 256, 256, 0, stream>>>(dst, degi, erank, E, eb, W1, W2, Wself, Wneigh, wfrag);
  k_scan_all<<<nb, 1024, 0, stream>>>(degi, bsum, boffG, rowstart, donecnt, flag, N, nb);

  const int gb = (N + 63) / 64;
  const int lb = (N + 15) / 16;
  const uint4* wf = (const uint4*)wfrag;

  // merged fc12 (first) + atomic-free ushort fill (behind)
  k_fill_fc<<<gb + eb, 256, 0, stream>>>(src, dst, erank, rowstart, esrc, E, gb,
                                         h_in, wf + 0 * 2048, wf + 1 * 2048, b1, b2,
                                         (unsigned short*)actB, N);

  const unsigned* cur = actB;
  unsigned* nxt = actA;
  for (int l = 0; l < 3; ++l) {
    const uint4* wsF = wf + (size_t)(2 + l) * 2048;
    const uint4* wnF = wf + (size_t)(5 + l) * 2048;
    const float* bs = bself + (size_t)l * DD;
    if (l < 2) {
      k_layer16<2, false><<<lb, 256, 0, stream>>>((const uint4*)cur, rowstart, esrc, wsF, wnF, bs, nxt, N);
      const unsigned* tmp = cur;
      cur = nxt;
      nxt = (unsigned*)tmp;
    } else {
      k_layer16<1, true><<<lb, 256, 0, stream>>>((const uint4*)cur, rowstart, esrc, wsF, wnF, bs, out, N);
    }
  }
}

// Round 21
// 278.985 us; speedup vs baseline: 4.6688x; 1.1060x over previous
//
#include <hip/hip_runtime.h>
#include <stdint.h>

#define DD 128
#define LDSROW 136  // 128 cols + 8 pad (ushort) -> 272B row stride

typedef __attribute__((ext_vector_type(8))) short short8;
typedef __attribute__((ext_vector_type(4))) float float4v;

// ---------- bf16 helpers (RTNE) ----------
__device__ __forceinline__ unsigned short f2bf(float f) {
  unsigned u = __float_as_uint(f);
  unsigned r = u + 0x7fffu + ((u >> 16) & 1u);
  return (unsigned short)(r >> 16);
}
__device__ __forceinline__ unsigned pack2(float a, float b) {
  return (unsigned)f2bf(a) | ((unsigned)f2bf(b) << 16);
}
__device__ __forceinline__ float2 unpack2(unsigned p) {
  float2 r;
  r.x = __uint_as_float(p << 16);
  r.y = __uint_as_float(p & 0xffff0000u);
  return r;
}

// ---------- CSR build pass A: deg atomics + per-edge rank (ushort) + weight prep fused ----------
__global__ __launch_bounds__(256) void k_deg_prep(const int* __restrict__ dst, int* deg,
                                                  unsigned short* __restrict__ erank,
                                                  int e, int eb,
                                                  const float* __restrict__ W1, const float* __restrict__ W2,
                                                  const float* __restrict__ Wself, const float* __restrict__ Wneigh,
                                                  unsigned* __restrict__ wfrag) {
  int b = blockIdx.x;
  if (b < eb) {
    int i = b * 256 + threadIdx.x;
    if (i < e) erank[i] = (unsigned short)atomicAdd(&deg[dst[i]], 1);
  } else {
    int gid = (b - eb) * 256 + threadIdx.x;  // 0 .. 65535
    int m = gid >> 13;
    int r = gid & 8191;
    int p = r & 3;
    int lane = (r >> 2) & 63;
    int t = (r >> 8) & 3;
    int c = r >> 10;
    const float* W;
    if (m == 0) W = W1;
    else if (m == 1) W = W2;
    else if (m < 5) W = Wself + (size_t)(m - 2) * DD * DD;
    else W = Wneigh + (size_t)(m - 5) * DD * DD;
    int n = c * 16 + (lane & 15);
    int k = t * 32 + (lane >> 4) * 8 + 2 * p;
    wfrag[gid] = pack2(W[(size_t)k * DD + n], W[(size_t)(k + 1) * DD + n]);
  }
}

__global__ __launch_bounds__(1024) void k_scan1(const int* __restrict__ deg, int* __restrict__ incl,
                                                int* __restrict__ bsum, int n) {
  __shared__ int sh[1024];
  int t = threadIdx.x;
  int i = blockIdx.x * 1024 + t;
  int v = (i < n) ? deg[i] : 0;
  sh[t] = v;
  __syncthreads();
#pragma unroll
  for (int off = 1; off < 1024; off <<= 1) {
    int add = (t >= off) ? sh[t - off] : 0;
    __syncthreads();
    sh[t] += add;
    __syncthreads();
  }
  if (i < n) incl[i] = sh[t];
  if (t == 1023) bsum[blockIdx.x] = sh[1023];
}

__global__ __launch_bounds__(1024) void k_scan3(const int* __restrict__ deg, const int* __restrict__ incl,
                                                const int* __restrict__ bsum, int* __restrict__ rowstart,
                                                int n, int nb) {
  __shared__ int sboff;
  int t = threadIdx.x;
  if (t < 64) {
    int orig = (t < nb) ? bsum[t] : 0;
    int v = orig;
#pragma unroll
    for (int off = 1; off < 64; off <<= 1) {
      int u = __shfl_up(v, off);
      if (t >= off) v += u;
    }
    if (t == (int)blockIdx.x) sboff = v - orig;
  }
  __syncthreads();
  int i = blockIdx.x * 1024 + t;
  if (i >= n) return;
  int d = deg[i];
  int excl = sboff + incl[i] - d;
  rowstart[i] = excl;
  if (i == n - 1) rowstart[n] = excl + d;
}

// ---------- merged: fused fc_in GEMM (blocks [0,gb)) + atomic-free CSR fill (blocks [gb,gb+fb)) ----------
__global__ __launch_bounds__(256) void k_fill_fc(const int* __restrict__ src, const int* __restrict__ dst,
                                                 const unsigned short* __restrict__ erank,
                                                 const int* __restrict__ rowstart,
                                                 unsigned short* __restrict__ esrc, int e, int gb,
                                                 const float* __restrict__ h,
                                                 const uint4* __restrict__ wf1, const uint4* __restrict__ wf2,
                                                 const float* __restrict__ b1, const float* __restrict__ b2,
                                                 unsigned short* __restrict__ outbf, int n) {
  __shared__ unsigned short sT[64 * LDSROW];
  int b = blockIdx.x;
  if (b >= gb) {
    int i = (b - gb) * 256 + threadIdx.x;
    if (i < e) {
      int d = dst[i];
      int p = rowstart[d] + (int)erank[i];
      esrc[p] = (unsigned short)src[i];
    }
    return;
  }
  // ---- fc12 body ----
  int tid = threadIdx.x, w = tid >> 6, lane = tid & 63;
  int q = lane >> 4, nn = lane & 15;
  int r0 = (b * 4 + w) * 16;
  int rr = r0 + nn; if (rr >= n) rr = n - 1;
  short8 a[4];
  {
    const float* X = h + (size_t)rr * DD;
#pragma unroll
    for (int t = 0; t < 4; ++t) {
      int k0 = t * 32 + q * 8;
      float4 f0 = *(const float4*)&X[k0];
      float4 f1 = *(const float4*)&X[k0 + 4];
      uint4 u;
      u.x = pack2(f0.x, f0.y); u.y = pack2(f0.z, f0.w);
      u.z = pack2(f1.x, f1.y); u.w = pack2(f1.z, f1.w);
      a[t] = __builtin_bit_cast(short8, u);
    }
  }
  float4v acc[8];
#pragma unroll
  for (int c = 0; c < 8; ++c) acc[c] = (float4v){0.f, 0.f, 0.f, 0.f};
#pragma unroll
  for (int c = 0; c < 8; ++c) {
#pragma unroll
    for (int t = 0; t < 4; ++t) {
      short8 bb = __builtin_bit_cast(short8, wf1[(c * 4 + t) * 64 + lane]);
      acc[c] = __builtin_amdgcn_mfma_f32_16x16x32_bf16(a[t], bb, acc[c], 0, 0, 0);
    }
  }
#pragma unroll
  for (int c = 0; c < 8; ++c) {
    float bc = b1[c * 16 + nn];
#pragma unroll
    for (int g = 0; g < 4; ++g) {
      int lr = w * 16 + q * 4 + g;
      sT[lr * LDSROW + c * 16 + nn] = f2bf(tanhf(acc[c][g] + bc));
    }
  }
  __syncthreads();
  short8 a2[4];
#pragma unroll
  for (int t = 0; t < 4; ++t) {
    const uint4* p = (const uint4*)&sT[(w * 16 + nn) * LDSROW + (t * 4 + q) * 8];
    a2[t] = __builtin_bit_cast(short8, *p);
  }
  float4v acc2[8];
#pragma unroll
  for (int c = 0; c < 8; ++c) acc2[c] = (float4v){0.f, 0.f, 0.f, 0.f};
#pragma unroll
  for (int c = 0; c < 8; ++c) {
#pragma unroll
    for (int t = 0; t < 4; ++t) {
      short8 bb = __builtin_bit_cast(short8, wf2[(c * 4 + t) * 64 + lane]);
      acc2[c] = __builtin_amdgcn_mfma_f32_16x16x32_bf16(a2[t], bb, acc2[c], 0, 0, 0);
    }
  }
#pragma unroll
  for (int c = 0; c < 8; ++c) {
    float bc = b2[c * 16 + nn];
#pragma unroll
    for (int g = 0; g < 4; ++g) {
      int row = r0 + q * 4 + g;
      if (row < n) outbf[(size_t)row * DD + c * 16 + nn] = f2bf(acc2[c][g] + bc);
    }
  }
}

// ---------- fused layer, 16 rows/block: aggregate (1 row per 16-lane group, 8-deep, masked tail) -> LDS -> SAGE GEMM ----------
// ACT: 1 tanh, 2 silu
template <int ACT, bool OUTF32>
__global__ __launch_bounds__(256) void k_layer16(const uint4* __restrict__ X,
                                                 const int* __restrict__ rowstart,
                                                 const unsigned short* __restrict__ esrc,
                                                 const uint4* __restrict__ wfs, const uint4* __restrict__ wfn,
                                                 const float* __restrict__ bias, void* __restrict__ outp, int n) {
  __shared__ unsigned short sG[16 * LDSROW];
  int tid = threadIdx.x;
  int grp = tid >> 4, nn = tid & 15;   // 16 groups x 16 lanes
  int r0 = blockIdx.x * 16;
  int r = r0 + grp;
  // ---- phase 1: aggregate row r; lane nn covers bf16 cols nn*8..nn*8+7 (one uint4) ----
  if (r < n) {
    int beg = rowstart[r];
    int cnt = rowstart[r + 1] - beg;
    float acc[8];
#pragma unroll
    for (int i = 0; i < 8; ++i) acc[i] = 0.f;
    int base = 0;
    for (; base + 8 <= cnt; base += 8) {  // 8 gathers in flight
      int j0 = beg + base;
      int s0 = esrc[j0], s1 = esrc[j0 + 1], s2 = esrc[j0 + 2], s3 = esrc[j0 + 3];
      int s4 = esrc[j0 + 4], s5 = esrc[j0 + 5], s6 = esrc[j0 + 6], s7 = esrc[j0 + 7];
      uint4 v0 = X[(size_t)s0 * 16 + nn];
      uint4 v1 = X[(size_t)s1 * 16 + nn];
      uint4 v2 = X[(size_t)s2 * 16 + nn];
      uint4 v3 = X[(size_t)s3 * 16 + nn];
      uint4 v4 = X[(size_t)s4 * 16 + nn];
      uint4 v5 = X[(size_t)s5 * 16 + nn];
      uint4 v6 = X[(size_t)s6 * 16 + nn];
      uint4 v7 = X[(size_t)s7 * 16 + nn];
      const unsigned* u0 = (const unsigned*)&v0;
      const unsigned* u1 = (const unsigned*)&v1;
      const unsigned* u2 = (const unsigned*)&v2;
      const unsigned* u3 = (const unsigned*)&v3;
      const unsigned* u4 = (const unsigned*)&v4;
      const unsigned* u5 = (const unsigned*)&v5;
      const unsigned* u6 = (const unsigned*)&v6;
      const unsigned* u7 = (const unsigned*)&v7;
#pragma unroll
      for (int k = 0; k < 4; ++k) {
        float2 f0 = unpack2(u0[k]), f1 = unpack2(u1[k]);
        float2 f2 = unpack2(u2[k]), f3 = unpack2(u3[k]);
        float2 f4 = unpack2(u4[k]), f5 = unpack2(u5[k]);
        float2 f6 = unpack2(u6[k]), f7 = unpack2(u7[k]);
        acc[2 * k]     += ((f0.x + f1.x) + (f2.x + f3.x)) + ((f4.x + f5.x) + (f6.x + f7.x));
        acc[2 * k + 1] += ((f0.y + f1.y) + (f2.y + f3.y)) + ((f4.y + f5.y) + (f6.y + f7.y));
      }
    }
    if (base < cnt) {  // masked 8-wide tail: clamp index (dup gathers hit cache), weight 0/1
      int last = beg + cnt - 1;
      int j0 = beg + base;
      int i1 = j0 + 1 <= last ? j0 + 1 : last;
      int i2 = j0 + 2 <= last ? j0 + 2 : last;
      int i3 = j0 + 3 <= last ? j0 + 3 : last;
      int i4 = j0 + 4 <= last ? j0 + 4 : last;
      int i5 = j0 + 5 <= last ? j0 + 5 : last;
      int i6 = j0 + 6 <= last ? j0 + 6 : last;
      int i7 = j0 + 7 <= last ? j0 + 7 : last;
      float w1 = (base + 1 < cnt) ? 1.f : 0.f;
      float w2 = (base + 2 < cnt) ? 1.f : 0.f;
      float w3 = (base + 3 < cnt) ? 1.f : 0.f;
      float w4 = (base + 4 < cnt) ? 1.f : 0.f;
      float w5 = (base + 5 < cnt) ? 1.f : 0.f;
      float w6 = (base + 6 < cnt) ? 1.f : 0.f;
      float w7 = (base + 7 < cnt) ? 1.f : 0.f;
      int s0 = esrc[j0], s1 = esrc[i1], s2 = esrc[i2], s3 = esrc[i3];
      int s4 = esrc[i4], s5 = esrc[i5], s6 = esrc[i6], s7 = esrc[i7];
      uint4 v0 = X[(size_t)s0 * 16 + nn];
      uint4 v1 = X[(size_t)s1 * 16 + nn];
      uint4 v2 = X[(size_t)s2 * 16 + nn];
      uint4 v3 = X[(size_t)s3 * 16 + nn];
      uint4 v4 = X[(size_t)s4 * 16 + nn];
      uint4 v5 = X[(size_t)s5 * 16 + nn];
      uint4 v6 = X[(size_t)s6 * 16 + nn];
      uint4 v7 = X[(size_t)s7 * 16 + nn];
      const unsigned* u0 = (const unsigned*)&v0;
      const unsigned* u1 = (const unsigned*)&v1;
      const unsigned* u2 = (const unsigned*)&v2;
      const unsigned* u3 = (const unsigned*)&v3;
      const unsigned* u4 = (const unsigned*)&v4;
      const unsigned* u5 = (const unsigned*)&v5;
      const unsigned* u6 = (const unsigned*)&v6;
      const unsigned* u7 = (const unsigned*)&v7;
#pragma unroll
      for (int k = 0; k < 4; ++k) {
        float2 f0 = unpack2(u0[k]), f1 = unpack2(u1[k]);
        float2 f2 = unpack2(u2[k]), f3 = unpack2(u3[k]);
        float2 f4 = unpack2(u4[k]), f5 = unpack2(u5[k]);
        float2 f6 = unpack2(u6[k]), f7 = unpack2(u7[k]);
        acc[2 * k]     += ((f0.x + w1 * f1.x) + (w2 * f2.x + w3 * f3.x)) + ((w4 * f4.x + w5 * f5.x) + (w6 * f6.x + w7 * f7.x));
        acc[2 * k + 1] += ((f0.y + w1 * f1.y) + (w2 * f2.y + w3 * f3.y)) + ((w4 * f4.y + w5 * f5.y) + (w6 * f6.y + w7 * f7.y));
      }
    }
    float inv = 1.0f / (float)(cnt > 1 ? cnt : 1);
    uint4 o;
    o.x = pack2(acc[0] * inv, acc[1] * inv);
    o.y = pack2(acc[2] * inv, acc[3] * inv);
    o.z = pack2(acc[4] * inv, acc[5] * inv);
    o.w = pack2(acc[6] * inv, acc[7] * inv);
    *(uint4*)&sG[grp * LDSROW + nn * 8] = o;
  }
  __syncthreads();
  // ---- phase 2: SAGE GEMM on rows r0..r0+15. wave w -> col-chunks {2w, 2w+1} ----
  int w = tid >> 6, lane = tid & 63;
  int q = lane >> 4, nn16 = lane & 15;
  int rr = r0 + nn16; if (rr >= n) rr = n - 1;
  short8 a[4], gf[4];
  {
    const uint4* Xr = X + (size_t)rr * 16;
#pragma unroll
    for (int t = 0; t < 4; ++t) {
      a[t] = __builtin_bit_cast(short8, Xr[t * 4 + q]);
      gf[t] = __builtin_bit_cast(short8, *(const uint4*)&sG[nn16 * LDSROW + (t * 4 + q) * 8]);
    }
  }
  float4v acc2[2];
#pragma unroll
  for (int cc = 0; cc < 2; ++cc) acc2[cc] = (float4v){0.f, 0.f, 0.f, 0.f};
#pragma unroll
  for (int cc = 0; cc < 2; ++cc) {
    int c = 2 * w + cc;
#pragma unroll
    for (int t = 0; t < 4; ++t) {
      short8 b = __builtin_bit_cast(short8, wfs[(c * 4 + t) * 64 + lane]);
      acc2[cc] = __builtin_amdgcn_mfma_f32_16x16x32_bf16(a[t], b, acc2[cc], 0, 0, 0);
    }
#pragma unroll
    for (int t = 0; t < 4; ++t) {
      short8 b = __builtin_bit_cast(short8, wfn[(c * 4 + t) * 64 + lane]);
      acc2[cc] = __builtin_amdgcn_mfma_f32_16x16x32_bf16(gf[t], b, acc2[cc], 0, 0, 0);
    }
  }
#pragma unroll
  for (int cc = 0; cc < 2; ++cc) {
    int c = 2 * w + cc;
    float bc = bias[c * 16 + nn16];
#pragma unroll
    for (int gg = 0; gg < 4; ++gg) {
      int row = r0 + q * 4 + gg;
      if (row < n) {
        float v = acc2[cc][gg] + bc;
        if (ACT == 1) v = tanhf(v);
        else v = v / (1.f + __expf(-v));
        if (OUTF32) ((float*)outp)[(size_t)row * DD + c * 16 + nn16] = v;
        else ((unsigned short*)outp)[(size_t)row * DD + c * 16 + nn16] = f2bf(v);
      }
    }
  }
}

extern "C" void kernel_launch(void* const* d_in, const int* in_sizes, int n_in,
                              void* d_out, int out_size, void* d_ws, size_t ws_size,
                              hipStream_t stream) {
  const float* h_in = (const float*)d_in[0];
  const int* src    = (const int*)d_in[1];
  const int* dst    = (const int*)d_in[2];
  const float* W1   = (const float*)d_in[3];
  const float* b1   = (const float*)d_in[4];
  const float* W2   = (const float*)d_in[5];
  const float* b2   = (const float*)d_in[6];
  const float* Wself  = (const float*)d_in[7];
  const float* bself  = (const float*)d_in[8];
  const float* Wneigh = (const float*)d_in[9];
  const int N = in_sizes[0] / DD;
  const int E = in_sizes[1];
  float* out = (float*)d_out;

  char* ws = (char*)d_ws;
  size_t off = 0;
  auto alloc = [&](size_t bytes) -> char* {
    char* p = ws + off;
    off = (off + bytes + 255) & ~(size_t)255;
    return p;
  };
  unsigned* wfrag = (unsigned*)alloc(8 * 32768);
  unsigned* actA  = (unsigned*)alloc((size_t)N * 64 * 4);
  unsigned* actB  = (unsigned*)alloc((size_t)N * 64 * 4);
  unsigned short* esrc  = (unsigned short*)alloc((size_t)E * 2);
  unsigned short* erank = (unsigned short*)alloc((size_t)E * 2);
  int* degi     = (int*)alloc((size_t)N * 4);
  int* rowstart = (int*)alloc((size_t)(N + 1) * 4);
  int* incl     = (int*)alloc((size_t)N * 4);
  int* bsum     = (int*)alloc(65 * 4);

  hipMemsetAsync(degi, 0, (size_t)N * 4, stream);
  const int eb = (E + 255) / 256;
  const int nb = (N + 1023) / 1024;
  k_deg_prep<<<eb + 256, 256, 0, stream>>>(dst, degi, erank, E, eb, W1, W2, Wself, Wneigh, wfrag);
  k_scan1<<<nb, 1024, 0, stream>>>(degi, incl, bsum, N);
  k_scan3<<<nb, 1024, 0, stream>>>(degi, incl, bsum, rowstart, N, nb);

  const int gb = (N + 63) / 64;
  const int lb = (N + 15) / 16;
  const uint4* wf = (const uint4*)wfrag;

  // merged fc12 (first) + atomic-free ushort fill (behind)
  k_fill_fc<<<gb + eb, 256, 0, stream>>>(src, dst, erank, rowstart, esrc, E, gb,
                                         h_in, wf + 0 * 2048, wf + 1 * 2048, b1, b2,
                                         (unsigned short*)actB, N);

  const unsigned* cur = actB;
  unsigned* nxt = actA;
  for (int l = 0; l < 3; ++l) {
    const uint4* wsF = wf + (size_t)(2 + l) * 2048;
    const uint4* wnF = wf + (size_t)(5 + l) * 2048;
    const float* bs = bself + (size_t)l * DD;
    if (l < 2) {
      k_layer16<2, false><<<lb, 256, 0, stream>>>((const uint4*)cur, rowstart, esrc, wsF, wnF, bs, nxt, N);
      const unsigned* tmp = cur;
      cur = nxt;
      nxt = (unsigned*)tmp;
    } else {
      k_layer16<1, true><<<lb, 256, 0, stream>>>((const uint4*)cur, rowstart, esrc, wsF, wnF, bs, out, N);
    }
  }
}